// Round 5
// baseline (683.497 us; speedup 1.0000x reference)
//
#include <hip/hip_runtime.h>
#include <cmath>

#define Bn 32768
#define Ln 256
#define Pn 1024
#define Dn 50
#define Cn 3
#define Sn 10

typedef short bf16x8 __attribute__((ext_vector_type(8)));
typedef float f32x4 __attribute__((ext_vector_type(4)));

__device__ inline unsigned short f2bf(float f) {
    unsigned int u = __float_as_uint(f);
    unsigned int r = (u + 0x7FFFu + ((u >> 16) & 1u)) >> 16;
    return (unsigned short)r;
}

// ---------------- pp softmax over axis=1 (p), per (c,n); also accumulates pps[c,p] ----------------
__global__ void pp_softmax_kernel(const float* __restrict__ pres, float* __restrict__ pp,
                                  float* __restrict__ pps) {
    int c = blockIdx.x / Sn;
    int n = blockIdx.x % Sn;
    int lane = threadIdx.x; // 64 threads
    const float* src = pres + (size_t)c * Pn * Sn + n;
    float* dst = pp + (size_t)c * Pn * Sn + n;
    float v[16];
    float mx = -1e30f;
#pragma unroll
    for (int i = 0; i < 16; ++i) { v[i] = src[(size_t)(lane + i * 64) * Sn]; mx = fmaxf(mx, v[i]); }
#pragma unroll
    for (int m = 1; m < 64; m <<= 1) mx = fmaxf(mx, __shfl_xor(mx, m, 64));
    float sum = 0.f;
#pragma unroll
    for (int i = 0; i < 16; ++i) { v[i] = __expf(v[i] - mx); sum += v[i]; }
#pragma unroll
    for (int m = 1; m < 64; m <<= 1) sum += __shfl_xor(sum, m, 64);
    float inv = 1.0f / sum;
#pragma unroll
    for (int i = 0; i < 16; ++i) {
        float r = v[i] * inv;
        dst[(size_t)(lane + i * 64) * Sn] = r;
        atomicAdd(&pps[c * Pn + lane + i * 64], r);
    }
}

// ---------------- projection: Linear(256->50) -> InstanceNorm -> ReLU -> Linear(50->50) ----------------
// (unchanged from R4 — evidence pending; it will surface in top-5 once sim drops)
__global__ __launch_bounds__(256) void project_kernel(
    const float* __restrict__ zin,
    const float* __restrict__ W1, const float* __restrict__ b1,
    const float* __restrict__ W2, const float* __restrict__ b2,
    float* __restrict__ outp, float* __restrict__ outn,
    unsigned short* __restrict__ outb)
{
    __shared__ float xs[64][68];
    __shared__ float w1t[64][68];
    __shared__ float w2t[52][68];

    int t = threadIdx.x;
    int tx = t & 15, ty = t >> 4;
    int row0 = blockIdx.x * 64;

    for (int idx = t; idx < 52 * 64; idx += 256) {
        int j = idx & 63, k = idx >> 6;
        w2t[k][j] = (j < Dn && k < Dn) ? W2[j * Dn + k] : 0.f;
    }

    float acc[4][4] = {};
    for (int kc = 0; kc < Ln; kc += 64) {
        __syncthreads();
        for (int idx = t; idx < 64 * 64; idx += 256) {
            int kk = idx & 63, r = idx >> 6;
            xs[r][kk] = zin[(size_t)(row0 + r) * Ln + kc + kk];
        }
        for (int idx = t; idx < 64 * 64; idx += 256) {
            int j = idx & 63, kk = idx >> 6;
            w1t[kk][j] = (j < Dn) ? W1[j * Ln + kc + kk] : 0.f;
        }
        __syncthreads();
#pragma unroll 4
        for (int k4 = 0; k4 < 16; ++k4) {
            float4 xv[4], wv[4];
#pragma unroll
            for (int i = 0; i < 4; ++i) xv[i] = *(const float4*)&xs[ty * 4 + i][k4 * 4];
#pragma unroll
            for (int kk = 0; kk < 4; ++kk) wv[kk] = *(const float4*)&w1t[k4 * 4 + kk][tx * 4];
#pragma unroll
            for (int i = 0; i < 4; ++i)
#pragma unroll
                for (int kk = 0; kk < 4; ++kk)
#pragma unroll
                    for (int j = 0; j < 4; ++j)
                        acc[i][j] += (&xv[i].x)[kk] * (&wv[kk].x)[j];
        }
    }

    float rb1[4], rb2[4];
    bool valid[4];
#pragma unroll
    for (int j = 0; j < 4; ++j) {
        int c = tx * 4 + j;
        valid[j] = c < Dn;
        rb1[j] = valid[j] ? b1[c] : 0.f;
        rb2[j] = valid[j] ? b2[c] : 0.f;
    }

    __syncthreads();

#pragma unroll
    for (int i = 0; i < 4; ++i) {
        float h[4];
        float s = 0.f;
#pragma unroll
        for (int j = 0; j < 4; ++j) { h[j] = acc[i][j] + rb1[j]; s += h[j]; }
#pragma unroll
        for (int m = 1; m < 16; m <<= 1) s += __shfl_xor(s, m, 64);
        float mean = s * (1.0f / Dn);
        float s2 = 0.f;
#pragma unroll
        for (int j = 0; j < 4; ++j) { float dv = valid[j] ? (h[j] - mean) : 0.f; s2 += dv * dv; }
#pragma unroll
        for (int m = 1; m < 16; m <<= 1) s2 += __shfl_xor(s2, m, 64);
        float rstd = rsqrtf(s2 * (1.0f / Dn) + 1e-5f);
        float4 rv;
#pragma unroll
        for (int j = 0; j < 4; ++j)
            (&rv.x)[j] = valid[j] ? fmaxf((h[j] - mean) * rstd, 0.f) : 0.f;
        *(float4*)&xs[ty * 4 + i][tx * 4] = rv;
    }
    __syncthreads();

    float acc2[4][4] = {};
#pragma unroll 4
    for (int k4 = 0; k4 < 13; ++k4) {
        float4 xv[4], wv[4];
#pragma unroll
        for (int i = 0; i < 4; ++i) xv[i] = *(const float4*)&xs[ty * 4 + i][k4 * 4];
#pragma unroll
        for (int kk = 0; kk < 4; ++kk) wv[kk] = *(const float4*)&w2t[k4 * 4 + kk][tx * 4];
#pragma unroll
        for (int i = 0; i < 4; ++i)
#pragma unroll
            for (int kk = 0; kk < 4; ++kk)
#pragma unroll
                for (int j = 0; j < 4; ++j)
                    acc2[i][j] += (&xv[i].x)[kk] * (&wv[kk].x)[j];
    }

#pragma unroll
    for (int i = 0; i < 4; ++i) {
        int row = row0 + ty * 4 + i;
        float o[4];
        float q = 0.f;
#pragma unroll
        for (int j = 0; j < 4; ++j) {
            o[j] = acc2[i][j] + rb2[j];
            if (valid[j]) q += o[j] * o[j];
            if (valid[j]) outp[(size_t)row * Dn + tx * 4 + j] = o[j];
        }
        ushort4 ob;
        ob.x = valid[0] ? f2bf(o[0]) : 0;
        ob.y = valid[1] ? f2bf(o[1]) : 0;
        ob.z = valid[2] ? f2bf(o[2]) : 0;
        ob.w = valid[3] ? f2bf(o[3]) : 0;
        *(ushort4*)&outb[(size_t)row * 64 + tx * 4] = ob;
#pragma unroll
        for (int m = 1; m < 16; m <<= 1) q += __shfl_xor(q, m, 64);
        if (tx == 0) outn[row] = q;
    }
}

// ---------------- sim via bf16 MFMA, 32 rows/block, double-buffered B loads ----------------
// grid 1024 blocks (4 blocks/CU), 4 waves; wave w covers protos w*256..+255 in 16 tiles of 16.
__global__ __launch_bounds__(256, 4) void sim_mfma_kernel(
    const unsigned short* __restrict__ xpb, const unsigned short* __restrict__ lpb,
    const float* __restrict__ xpn, const float* __restrict__ lpn,
    const float* __restrict__ pps,
    float* __restrict__ sim, float* __restrict__ out1)
{
    int t = threadIdx.x;
    int w = t >> 6, l = t & 63;
    int lr = l & 15, lg = l >> 4;
    int row0 = blockIdx.x * 32;

    bf16x8 af[2][2];
#pragma unroll
    for (int m = 0; m < 2; ++m)
#pragma unroll
        for (int ks = 0; ks < 2; ++ks)
            af[m][ks] = *(const bf16x8*)&xpb[(size_t)(row0 + m * 16 + lr) * 64 + ks * 32 + lg * 8];

    float xnr[2][4];
#pragma unroll
    for (int m = 0; m < 2; ++m)
#pragma unroll
        for (int i = 0; i < 4; ++i)
            xnr[m][i] = xpn[row0 + m * 16 + lg * 4 + i];

    float oacc[2][4][3] = {};  // [m][i][c]

    // double-buffered proto-side state
    bf16x8 bfr[2][2];
    float lnv[2], p0v[2], p1v[2], p2v[2];
    {
        int pc = w * 256;
#pragma unroll
        for (int ks = 0; ks < 2; ++ks)
            bfr[0][ks] = *(const bf16x8*)&lpb[(size_t)(pc + lr) * 64 + ks * 32 + lg * 8];
        lnv[0] = lpn[pc + lr];
        p0v[0] = pps[pc + lr];
        p1v[0] = pps[Pn + pc + lr];
        p2v[0] = pps[2 * Pn + pc + lr];
    }

    for (int tt = 0; tt < 16; ++tt) {
        int cur = tt & 1, nxt = cur ^ 1;
        if (tt < 15) {
            int pc = w * 256 + (tt + 1) * 16;
#pragma unroll
            for (int ks = 0; ks < 2; ++ks)
                bfr[nxt][ks] = *(const bf16x8*)&lpb[(size_t)(pc + lr) * 64 + ks * 32 + lg * 8];
            lnv[nxt] = lpn[pc + lr];
            p0v[nxt] = pps[pc + lr];
            p1v[nxt] = pps[Pn + pc + lr];
            p2v[nxt] = pps[2 * Pn + pc + lr];
        }
        int pc = w * 256 + tt * 16;

        f32x4 acc[2];
#pragma unroll
        for (int m = 0; m < 2; ++m) { f32x4 z = {0.f, 0.f, 0.f, 0.f}; acc[m] = z; }
#pragma unroll
        for (int ks = 0; ks < 2; ++ks)
#pragma unroll
            for (int m = 0; m < 2; ++m)
                acc[m] = __builtin_amdgcn_mfma_f32_16x16x32_bf16(af[m][ks], bfr[cur][ks], acc[m], 0, 0, 0);

        float ln = lnv[cur], pr0 = p0v[cur], pr1 = p1v[cur], pr2 = p2v[cur];
#pragma unroll
        for (int m = 0; m < 2; ++m)
#pragma unroll
            for (int i = 0; i < 4; ++i) {
                float l2 = xnr[m][i] + ln - 2.f * acc[m][i];
                l2 = fmaxf(l2, 0.f);
                float s = __logf(__fdividef(l2 + 1.f, l2 + 1e-5f));
                sim[(size_t)(row0 + m * 16 + lg * 4 + i) * Pn + pc + lr] = s;
                oacc[m][i][0] += s * pr0;
                oacc[m][i][1] += s * pr1;
                oacc[m][i][2] += s * pr2;
            }
    }

#pragma unroll
    for (int m = 0; m < 2; ++m)
#pragma unroll
        for (int i = 0; i < 4; ++i)
#pragma unroll
            for (int c = 0; c < 3; ++c) {
                float v = oacc[m][i][c];
                v += __shfl_xor(v, 1, 64);
                v += __shfl_xor(v, 2, 64);
                v += __shfl_xor(v, 4, 64);
                v += __shfl_xor(v, 8, 64);
                if (lr == 0)
                    atomicAdd(&out1[(size_t)(row0 + m * 16 + lg * 4 + i) * Cn + c], v);
            }
}

__global__ void finalize_kernel(const float* __restrict__ o1, float* __restrict__ out2) {
    int i = blockIdx.x * 256 + threadIdx.x;
    if (i < Bn * Cn) {
        float v = o1[i];
        int c = i - (i / Cn) * Cn;
        out2[i] = (c == 0) ? tanhf(v) : fmaxf(v, 0.f);
    }
}

extern "C" void kernel_launch(void* const* d_in, const int* in_sizes, int n_in,
                              void* d_out, int out_size, void* d_ws, size_t ws_size,
                              hipStream_t stream) {
    const float* x    = (const float*)d_in[0];
    const float* prot = (const float*)d_in[2];
    const float* pres = (const float*)d_in[3];
    const float* W1   = (const float*)d_in[4];
    const float* b1   = (const float*)d_in[5];
    const float* W2   = (const float*)d_in[6];
    const float* b2   = (const float*)d_in[7];

    float* out  = (float*)d_out;
    float* out2 = out;                           // [B,3]
    float* xp   = out + (size_t)Bn * Cn;         // [B,50]
    float* sim  = xp + (size_t)Bn * Dn;          // [B,1024]
    float* pp   = sim + (size_t)Bn * Pn;         // [3,1024,10]

    float* ws     = (float*)d_ws;
    float* out1ws = ws;                          // [B,3]
    float* pps    = out1ws + (size_t)Bn * Cn;    // [3,P]  (adjacent -> one memset)
    float* xpn    = pps + Cn * Pn;               // [B]
    float* lpn    = xpn + Bn;                    // [P]
    float* lpf    = lpn + Pn;                    // [P,50] fp32 proto projection (unused downstream)
    unsigned short* xpb = (unsigned short*)(lpf + Pn * Dn);  // [B,64] bf16
    unsigned short* lpb = xpb + (size_t)Bn * 64;             // [P,64] bf16

    hipMemsetAsync(out1ws, 0, ((size_t)Bn * Cn + Cn * Pn) * sizeof(float), stream);
    hipLaunchKernelGGL(pp_softmax_kernel, dim3(Cn * Sn), dim3(64), 0, stream, pres, pp, pps);
    hipLaunchKernelGGL(project_kernel, dim3(Bn / 64), dim3(256), 0, stream,
                       x, W1, b1, W2, b2, xp, xpn, xpb);
    hipLaunchKernelGGL(project_kernel, dim3(Pn / 64), dim3(256), 0, stream,
                       prot, W1, b1, W2, b2, lpf, lpn, lpb);
    hipLaunchKernelGGL(sim_mfma_kernel, dim3(Bn / 32), dim3(256), 0, stream,
                       xpb, lpb, xpn, lpn, pps, sim, out1ws);
    hipLaunchKernelGGL(finalize_kernel, dim3((Bn * Cn + 255) / 256), dim3(256), 0, stream,
                       out1ws, out2);
}

// Round 6
// 668.110 us; speedup vs baseline: 1.0230x; 1.0230x over previous
//
#include <hip/hip_runtime.h>
#include <cmath>

#define Bn 32768
#define Ln 256
#define Pn 1024
#define Dn 50
#define Cn 3
#define Sn 10

typedef short bf16x8 __attribute__((ext_vector_type(8)));
typedef float f32x4 __attribute__((ext_vector_type(4)));

__device__ inline unsigned short f2bf(float f) {
    unsigned int u = __float_as_uint(f);
    unsigned int r = (u + 0x7FFFu + ((u >> 16) & 1u)) >> 16;
    return (unsigned short)r;
}

// ---------------- pp softmax over axis=1 (p), per (c,n); also accumulates pps[c,p] ----------------
__global__ void pp_softmax_kernel(const float* __restrict__ pres, float* __restrict__ pp,
                                  float* __restrict__ pps) {
    int c = blockIdx.x / Sn;
    int n = blockIdx.x % Sn;
    int lane = threadIdx.x; // 64 threads
    const float* src = pres + (size_t)c * Pn * Sn + n;
    float* dst = pp + (size_t)c * Pn * Sn + n;
    float v[16];
    float mx = -1e30f;
#pragma unroll
    for (int i = 0; i < 16; ++i) { v[i] = src[(size_t)(lane + i * 64) * Sn]; mx = fmaxf(mx, v[i]); }
#pragma unroll
    for (int m = 1; m < 64; m <<= 1) mx = fmaxf(mx, __shfl_xor(mx, m, 64));
    float sum = 0.f;
#pragma unroll
    for (int i = 0; i < 16; ++i) { v[i] = __expf(v[i] - mx); sum += v[i]; }
#pragma unroll
    for (int m = 1; m < 64; m <<= 1) sum += __shfl_xor(sum, m, 64);
    float inv = 1.0f / sum;
#pragma unroll
    for (int i = 0; i < 16; ++i) {
        float r = v[i] * inv;
        dst[(size_t)(lane + i * 64) * Sn] = r;
        atomicAdd(&pps[c * Pn + lane + i * 64], r);
    }
}

// ---------------- projection: Linear(256->50) -> InstanceNorm -> ReLU -> Linear(50->50) ----------------
__global__ __launch_bounds__(256) void project_kernel(
    const float* __restrict__ zin,
    const float* __restrict__ W1, const float* __restrict__ b1,
    const float* __restrict__ W2, const float* __restrict__ b2,
    float* __restrict__ outp, float* __restrict__ outn,
    unsigned short* __restrict__ outb)
{
    __shared__ float xs[64][68];
    __shared__ float w1t[64][68];
    __shared__ float w2t[52][68];

    int t = threadIdx.x;
    int tx = t & 15, ty = t >> 4;
    int row0 = blockIdx.x * 64;

    for (int idx = t; idx < 52 * 64; idx += 256) {
        int j = idx & 63, k = idx >> 6;
        w2t[k][j] = (j < Dn && k < Dn) ? W2[j * Dn + k] : 0.f;
    }

    float acc[4][4] = {};
    for (int kc = 0; kc < Ln; kc += 64) {
        __syncthreads();
        for (int idx = t; idx < 64 * 64; idx += 256) {
            int kk = idx & 63, r = idx >> 6;
            xs[r][kk] = zin[(size_t)(row0 + r) * Ln + kc + kk];
        }
        for (int idx = t; idx < 64 * 64; idx += 256) {
            int j = idx & 63, kk = idx >> 6;
            w1t[kk][j] = (j < Dn) ? W1[j * Ln + kc + kk] : 0.f;
        }
        __syncthreads();
#pragma unroll 4
        for (int k4 = 0; k4 < 16; ++k4) {
            float4 xv[4], wv[4];
#pragma unroll
            for (int i = 0; i < 4; ++i) xv[i] = *(const float4*)&xs[ty * 4 + i][k4 * 4];
#pragma unroll
            for (int kk = 0; kk < 4; ++kk) wv[kk] = *(const float4*)&w1t[k4 * 4 + kk][tx * 4];
#pragma unroll
            for (int i = 0; i < 4; ++i)
#pragma unroll
                for (int kk = 0; kk < 4; ++kk)
#pragma unroll
                    for (int j = 0; j < 4; ++j)
                        acc[i][j] += (&xv[i].x)[kk] * (&wv[kk].x)[j];
        }
    }

    float rb1[4], rb2[4];
    bool valid[4];
#pragma unroll
    for (int j = 0; j < 4; ++j) {
        int c = tx * 4 + j;
        valid[j] = c < Dn;
        rb1[j] = valid[j] ? b1[c] : 0.f;
        rb2[j] = valid[j] ? b2[c] : 0.f;
    }

    __syncthreads();

#pragma unroll
    for (int i = 0; i < 4; ++i) {
        float h[4];
        float s = 0.f;
#pragma unroll
        for (int j = 0; j < 4; ++j) { h[j] = acc[i][j] + rb1[j]; s += h[j]; }
#pragma unroll
        for (int m = 1; m < 16; m <<= 1) s += __shfl_xor(s, m, 64);
        float mean = s * (1.0f / Dn);
        float s2 = 0.f;
#pragma unroll
        for (int j = 0; j < 4; ++j) { float dv = valid[j] ? (h[j] - mean) : 0.f; s2 += dv * dv; }
#pragma unroll
        for (int m = 1; m < 16; m <<= 1) s2 += __shfl_xor(s2, m, 64);
        float rstd = rsqrtf(s2 * (1.0f / Dn) + 1e-5f);
        float4 rv;
#pragma unroll
        for (int j = 0; j < 4; ++j)
            (&rv.x)[j] = valid[j] ? fmaxf((h[j] - mean) * rstd, 0.f) : 0.f;
        *(float4*)&xs[ty * 4 + i][tx * 4] = rv;
    }
    __syncthreads();

    float acc2[4][4] = {};
#pragma unroll 4
    for (int k4 = 0; k4 < 13; ++k4) {
        float4 xv[4], wv[4];
#pragma unroll
        for (int i = 0; i < 4; ++i) xv[i] = *(const float4*)&xs[ty * 4 + i][k4 * 4];
#pragma unroll
        for (int kk = 0; kk < 4; ++kk) wv[kk] = *(const float4*)&w2t[k4 * 4 + kk][tx * 4];
#pragma unroll
        for (int i = 0; i < 4; ++i)
#pragma unroll
            for (int kk = 0; kk < 4; ++kk)
#pragma unroll
                for (int j = 0; j < 4; ++j)
                    acc2[i][j] += (&xv[i].x)[kk] * (&wv[kk].x)[j];
    }

#pragma unroll
    for (int i = 0; i < 4; ++i) {
        int row = row0 + ty * 4 + i;
        float o[4];
        float q = 0.f;
#pragma unroll
        for (int j = 0; j < 4; ++j) {
            o[j] = acc2[i][j] + rb2[j];
            if (valid[j]) q += o[j] * o[j];
            if (valid[j]) outp[(size_t)row * Dn + tx * 4 + j] = o[j];
        }
        ushort4 ob;
        ob.x = valid[0] ? f2bf(o[0]) : 0;
        ob.y = valid[1] ? f2bf(o[1]) : 0;
        ob.z = valid[2] ? f2bf(o[2]) : 0;
        ob.w = valid[3] ? f2bf(o[3]) : 0;
        *(ushort4*)&outb[(size_t)row * 64 + tx * 4] = ob;
#pragma unroll
        for (int m = 1; m < 16; m <<= 1) q += __shfl_xor(q, m, 64);
        if (tx == 0) outn[row] = q;
    }
}

// ---------------- sim via bf16 MFMA, 32 rows/block, double-buffered B loads ----------------
// grid 1024 blocks, 4 waves; wave w covers protos w*256..+255 in 16 tiles of 16.
// launch_bounds(256,3): cap VGPR ~168 — do NOT force 4 waves (R5: forced 64 VGPR -> spill, 5x slower)
__global__ __launch_bounds__(256, 3) void sim_mfma_kernel(
    const unsigned short* __restrict__ xpb, const unsigned short* __restrict__ lpb,
    const float* __restrict__ xpn, const float* __restrict__ lpn,
    const float* __restrict__ pps,
    float* __restrict__ sim, float* __restrict__ out1)
{
    int t = threadIdx.x;
    int w = t >> 6, l = t & 63;
    int lr = l & 15, lg = l >> 4;
    int row0 = blockIdx.x * 32;

    bf16x8 af[2][2];
#pragma unroll
    for (int m = 0; m < 2; ++m)
#pragma unroll
        for (int ks = 0; ks < 2; ++ks)
            af[m][ks] = *(const bf16x8*)&xpb[(size_t)(row0 + m * 16 + lr) * 64 + ks * 32 + lg * 8];

    float xnr[2][4];
#pragma unroll
    for (int m = 0; m < 2; ++m)
#pragma unroll
        for (int i = 0; i < 4; ++i)
            xnr[m][i] = xpn[row0 + m * 16 + lg * 4 + i];

    float oacc[2][4][3] = {};  // [m][i][c]

    // double-buffered proto-side state
    bf16x8 bfr[2][2];
    float lnv[2], p0v[2], p1v[2], p2v[2];
    {
        int pc = w * 256;
#pragma unroll
        for (int ks = 0; ks < 2; ++ks)
            bfr[0][ks] = *(const bf16x8*)&lpb[(size_t)(pc + lr) * 64 + ks * 32 + lg * 8];
        lnv[0] = lpn[pc + lr];
        p0v[0] = pps[pc + lr];
        p1v[0] = pps[Pn + pc + lr];
        p2v[0] = pps[2 * Pn + pc + lr];
    }

    for (int tt = 0; tt < 16; ++tt) {
        int cur = tt & 1, nxt = cur ^ 1;
        if (tt < 15) {
            int pc = w * 256 + (tt + 1) * 16;
#pragma unroll
            for (int ks = 0; ks < 2; ++ks)
                bfr[nxt][ks] = *(const bf16x8*)&lpb[(size_t)(pc + lr) * 64 + ks * 32 + lg * 8];
            lnv[nxt] = lpn[pc + lr];
            p0v[nxt] = pps[pc + lr];
            p1v[nxt] = pps[Pn + pc + lr];
            p2v[nxt] = pps[2 * Pn + pc + lr];
        }
        int pc = w * 256 + tt * 16;

        f32x4 acc[2];
#pragma unroll
        for (int m = 0; m < 2; ++m) { f32x4 z = {0.f, 0.f, 0.f, 0.f}; acc[m] = z; }
#pragma unroll
        for (int ks = 0; ks < 2; ++ks)
#pragma unroll
            for (int m = 0; m < 2; ++m)
                acc[m] = __builtin_amdgcn_mfma_f32_16x16x32_bf16(af[m][ks], bfr[cur][ks], acc[m], 0, 0, 0);

        float ln = lnv[cur], pr0 = p0v[cur], pr1 = p1v[cur], pr2 = p2v[cur];
#pragma unroll
        for (int m = 0; m < 2; ++m)
#pragma unroll
            for (int i = 0; i < 4; ++i) {
                float l2 = xnr[m][i] + ln - 2.f * acc[m][i];
                l2 = fmaxf(l2, 0.f);
                float s = __logf(__fdividef(l2 + 1.f, l2 + 1e-5f));
                sim[(size_t)(row0 + m * 16 + lg * 4 + i) * Pn + pc + lr] = s;
                oacc[m][i][0] += s * pr0;
                oacc[m][i][1] += s * pr1;
                oacc[m][i][2] += s * pr2;
            }
    }

#pragma unroll
    for (int m = 0; m < 2; ++m)
#pragma unroll
        for (int i = 0; i < 4; ++i)
#pragma unroll
            for (int c = 0; c < 3; ++c) {
                float v = oacc[m][i][c];
                v += __shfl_xor(v, 1, 64);
                v += __shfl_xor(v, 2, 64);
                v += __shfl_xor(v, 4, 64);
                v += __shfl_xor(v, 8, 64);
                if (lr == 0)
                    atomicAdd(&out1[(size_t)(row0 + m * 16 + lg * 4 + i) * Cn + c], v);
            }
}

__global__ void finalize_kernel(const float* __restrict__ o1, float* __restrict__ out2) {
    int i = blockIdx.x * 256 + threadIdx.x;
    if (i < Bn * Cn) {
        float v = o1[i];
        int c = i - (i / Cn) * Cn;
        out2[i] = (c == 0) ? tanhf(v) : fmaxf(v, 0.f);
    }
}

extern "C" void kernel_launch(void* const* d_in, const int* in_sizes, int n_in,
                              void* d_out, int out_size, void* d_ws, size_t ws_size,
                              hipStream_t stream) {
    const float* x    = (const float*)d_in[0];
    const float* prot = (const float*)d_in[2];
    const float* pres = (const float*)d_in[3];
    const float* W1   = (const float*)d_in[4];
    const float* b1   = (const float*)d_in[5];
    const float* W2   = (const float*)d_in[6];
    const float* b2   = (const float*)d_in[7];

    float* out  = (float*)d_out;
    float* out2 = out;                           // [B,3]
    float* xp   = out + (size_t)Bn * Cn;         // [B,50]
    float* sim  = xp + (size_t)Bn * Dn;          // [B,1024]
    float* pp   = sim + (size_t)Bn * Pn;         // [3,1024,10]

    float* ws     = (float*)d_ws;
    float* out1ws = ws;                          // [B,3]
    float* pps    = out1ws + (size_t)Bn * Cn;    // [3,P]  (adjacent -> one memset)
    float* xpn    = pps + Cn * Pn;               // [B]
    float* lpn    = xpn + Bn;                    // [P]
    float* lpf    = lpn + Pn;                    // [P,50] fp32 proto projection (unused downstream)
    unsigned short* xpb = (unsigned short*)(lpf + Pn * Dn);  // [B,64] bf16
    unsigned short* lpb = xpb + (size_t)Bn * 64;             // [P,64] bf16

    hipMemsetAsync(out1ws, 0, ((size_t)Bn * Cn + Cn * Pn) * sizeof(float), stream);
    hipLaunchKernelGGL(pp_softmax_kernel, dim3(Cn * Sn), dim3(64), 0, stream, pres, pp, pps);
    hipLaunchKernelGGL(project_kernel, dim3(Bn / 64), dim3(256), 0, stream,
                       x, W1, b1, W2, b2, xp, xpn, xpb);
    hipLaunchKernelGGL(project_kernel, dim3(Pn / 64), dim3(256), 0, stream,
                       prot, W1, b1, W2, b2, lpf, lpn, lpb);
    hipLaunchKernelGGL(sim_mfma_kernel, dim3(Bn / 32), dim3(256), 0, stream,
                       xpb, lpb, xpn, lpn, pps, sim, out1ws);
    hipLaunchKernelGGL(finalize_kernel, dim3((Bn * Cn + 255) / 256), dim3(256), 0, stream,
                       out1ws, out2);
}

// Round 7
// 289.405 us; speedup vs baseline: 2.3617x; 2.3086x over previous
//
#include <hip/hip_runtime.h>
#include <cmath>

#define Bn 32768
#define Ln 256
#define Pn 1024
#define Dn 50
#define Cn 3
#define Sn 10

typedef short bf16x8 __attribute__((ext_vector_type(8)));
typedef float f32x4 __attribute__((ext_vector_type(4)));

__device__ inline unsigned short f2bf(float f) {
    unsigned int u = __float_as_uint(f);
    unsigned int r = (u + 0x7FFFu + ((u >> 16) & 1u)) >> 16;
    return (unsigned short)r;
}

// ---------------- pp softmax over axis=1 (p), per (c,n); also accumulates pps[c,p] ----------------
__global__ void pp_softmax_kernel(const float* __restrict__ pres, float* __restrict__ pp,
                                  float* __restrict__ pps) {
    int c = blockIdx.x / Sn;
    int n = blockIdx.x % Sn;
    int lane = threadIdx.x; // 64 threads
    const float* src = pres + (size_t)c * Pn * Sn + n;
    float* dst = pp + (size_t)c * Pn * Sn + n;
    float v[16];
    float mx = -1e30f;
#pragma unroll
    for (int i = 0; i < 16; ++i) { v[i] = src[(size_t)(lane + i * 64) * Sn]; mx = fmaxf(mx, v[i]); }
#pragma unroll
    for (int m = 1; m < 64; m <<= 1) mx = fmaxf(mx, __shfl_xor(mx, m, 64));
    float sum = 0.f;
#pragma unroll
    for (int i = 0; i < 16; ++i) { v[i] = __expf(v[i] - mx); sum += v[i]; }
#pragma unroll
    for (int m = 1; m < 64; m <<= 1) sum += __shfl_xor(sum, m, 64);
    float inv = 1.0f / sum;
#pragma unroll
    for (int i = 0; i < 16; ++i) {
        float r = v[i] * inv;
        dst[(size_t)(lane + i * 64) * Sn] = r;
        atomicAdd(&pps[c * Pn + lane + i * 64], r);
    }
}

// ---------------- projection: Linear(256->50) -> InstanceNorm -> ReLU -> Linear(50->50) ----------------
__global__ __launch_bounds__(256) void project_kernel(
    const float* __restrict__ zin,
    const float* __restrict__ W1, const float* __restrict__ b1,
    const float* __restrict__ W2, const float* __restrict__ b2,
    float* __restrict__ outp, float* __restrict__ outn,
    unsigned short* __restrict__ outb)
{
    __shared__ float xs[64][68];
    __shared__ float w1t[64][68];
    __shared__ float w2t[52][68];

    int t = threadIdx.x;
    int tx = t & 15, ty = t >> 4;
    int row0 = blockIdx.x * 64;

    for (int idx = t; idx < 52 * 64; idx += 256) {
        int j = idx & 63, k = idx >> 6;
        w2t[k][j] = (j < Dn && k < Dn) ? W2[j * Dn + k] : 0.f;
    }

    float acc[4][4] = {};
    for (int kc = 0; kc < Ln; kc += 64) {
        __syncthreads();
        for (int idx = t; idx < 64 * 64; idx += 256) {
            int kk = idx & 63, r = idx >> 6;
            xs[r][kk] = zin[(size_t)(row0 + r) * Ln + kc + kk];
        }
        for (int idx = t; idx < 64 * 64; idx += 256) {
            int j = idx & 63, kk = idx >> 6;
            w1t[kk][j] = (j < Dn) ? W1[j * Ln + kc + kk] : 0.f;
        }
        __syncthreads();
#pragma unroll 4
        for (int k4 = 0; k4 < 16; ++k4) {
            float4 xv[4], wv[4];
#pragma unroll
            for (int i = 0; i < 4; ++i) xv[i] = *(const float4*)&xs[ty * 4 + i][k4 * 4];
#pragma unroll
            for (int kk = 0; kk < 4; ++kk) wv[kk] = *(const float4*)&w1t[k4 * 4 + kk][tx * 4];
#pragma unroll
            for (int i = 0; i < 4; ++i)
#pragma unroll
                for (int kk = 0; kk < 4; ++kk)
#pragma unroll
                    for (int j = 0; j < 4; ++j)
                        acc[i][j] += (&xv[i].x)[kk] * (&wv[kk].x)[j];
        }
    }

    float rb1[4], rb2[4];
    bool valid[4];
#pragma unroll
    for (int j = 0; j < 4; ++j) {
        int c = tx * 4 + j;
        valid[j] = c < Dn;
        rb1[j] = valid[j] ? b1[c] : 0.f;
        rb2[j] = valid[j] ? b2[c] : 0.f;
    }

    __syncthreads();

#pragma unroll
    for (int i = 0; i < 4; ++i) {
        float h[4];
        float s = 0.f;
#pragma unroll
        for (int j = 0; j < 4; ++j) { h[j] = acc[i][j] + rb1[j]; s += h[j]; }
#pragma unroll
        for (int m = 1; m < 16; m <<= 1) s += __shfl_xor(s, m, 64);
        float mean = s * (1.0f / Dn);
        float s2 = 0.f;
#pragma unroll
        for (int j = 0; j < 4; ++j) { float dv = valid[j] ? (h[j] - mean) : 0.f; s2 += dv * dv; }
#pragma unroll
        for (int m = 1; m < 16; m <<= 1) s2 += __shfl_xor(s2, m, 64);
        float rstd = rsqrtf(s2 * (1.0f / Dn) + 1e-5f);
        float4 rv;
#pragma unroll
        for (int j = 0; j < 4; ++j)
            (&rv.x)[j] = valid[j] ? fmaxf((h[j] - mean) * rstd, 0.f) : 0.f;
        *(float4*)&xs[ty * 4 + i][tx * 4] = rv;
    }
    __syncthreads();

    float acc2[4][4] = {};
#pragma unroll 4
    for (int k4 = 0; k4 < 13; ++k4) {
        float4 xv[4], wv[4];
#pragma unroll
        for (int i = 0; i < 4; ++i) xv[i] = *(const float4*)&xs[ty * 4 + i][k4 * 4];
#pragma unroll
        for (int kk = 0; kk < 4; ++kk) wv[kk] = *(const float4*)&w2t[k4 * 4 + kk][tx * 4];
#pragma unroll
        for (int i = 0; i < 4; ++i)
#pragma unroll
            for (int kk = 0; kk < 4; ++kk)
#pragma unroll
                for (int j = 0; j < 4; ++j)
                    acc2[i][j] += (&xv[i].x)[kk] * (&wv[kk].x)[j];
    }

#pragma unroll
    for (int i = 0; i < 4; ++i) {
        int row = row0 + ty * 4 + i;
        float o[4];
        float q = 0.f;
#pragma unroll
        for (int j = 0; j < 4; ++j) {
            o[j] = acc2[i][j] + rb2[j];
            if (valid[j]) q += o[j] * o[j];
            if (valid[j]) outp[(size_t)row * Dn + tx * 4 + j] = o[j];
        }
        ushort4 ob;
        ob.x = valid[0] ? f2bf(o[0]) : 0;
        ob.y = valid[1] ? f2bf(o[1]) : 0;
        ob.z = valid[2] ? f2bf(o[2]) : 0;
        ob.w = valid[3] ? f2bf(o[3]) : 0;
        *(ushort4*)&outb[(size_t)row * 64 + tx * 4] = ob;
#pragma unroll
        for (int m = 1; m < 16; m <<= 1) q += __shfl_xor(q, m, 64);
        if (tx == 0) outn[row] = q;
    }
}

// ---------------- sim via bf16 MFMA, 32 rows/block, STATIC double-buffer (rule #20 fix) ----------------
struct ProtoTile {
    bf16x8 b0, b1;
    float ln, p0, p1, p2;
};

__device__ __forceinline__ void load_tile(ProtoTile& T,
    const unsigned short* __restrict__ lpb, const float* __restrict__ lpn,
    const float* __restrict__ pps, int pc, int lr, int lg)
{
    T.b0 = *(const bf16x8*)&lpb[(size_t)(pc + lr) * 64 + lg * 8];
    T.b1 = *(const bf16x8*)&lpb[(size_t)(pc + lr) * 64 + 32 + lg * 8];
    T.ln = lpn[pc + lr];
    T.p0 = pps[pc + lr];
    T.p1 = pps[Pn + pc + lr];
    T.p2 = pps[2 * Pn + pc + lr];
}

__device__ __forceinline__ void compute_tile(const ProtoTile& T,
    const bf16x8 af[2][2], const float xnr[2][4], float oacc[2][4][3],
    float* __restrict__ sim, int row0, int pc, int lr, int lg)
{
    f32x4 acc[2];
#pragma unroll
    for (int m = 0; m < 2; ++m) { f32x4 z = {0.f, 0.f, 0.f, 0.f}; acc[m] = z; }
#pragma unroll
    for (int m = 0; m < 2; ++m) {
        acc[m] = __builtin_amdgcn_mfma_f32_16x16x32_bf16(af[m][0], T.b0, acc[m], 0, 0, 0);
        acc[m] = __builtin_amdgcn_mfma_f32_16x16x32_bf16(af[m][1], T.b1, acc[m], 0, 0, 0);
    }
#pragma unroll
    for (int m = 0; m < 2; ++m)
#pragma unroll
        for (int i = 0; i < 4; ++i) {
            float l2 = xnr[m][i] + T.ln - 2.f * acc[m][i];
            l2 = fmaxf(l2, 0.f);
            float s = __logf(__fdividef(l2 + 1.f, l2 + 1e-5f));
            sim[(size_t)(row0 + m * 16 + lg * 4 + i) * Pn + pc + lr] = s;
            oacc[m][i][0] += s * T.p0;
            oacc[m][i][1] += s * T.p1;
            oacc[m][i][2] += s * T.p2;
        }
}

__global__ __launch_bounds__(256) void sim_mfma_kernel(
    const unsigned short* __restrict__ xpb, const unsigned short* __restrict__ lpb,
    const float* __restrict__ xpn, const float* __restrict__ lpn,
    const float* __restrict__ pps,
    float* __restrict__ sim, float* __restrict__ out1)
{
    int t = threadIdx.x;
    int w = t >> 6, l = t & 63;
    int lr = l & 15, lg = l >> 4;
    int row0 = blockIdx.x * 32;
    int pbase = w * 256;

    bf16x8 af[2][2];
#pragma unroll
    for (int m = 0; m < 2; ++m)
#pragma unroll
        for (int ks = 0; ks < 2; ++ks)
            af[m][ks] = *(const bf16x8*)&xpb[(size_t)(row0 + m * 16 + lr) * 64 + ks * 32 + lg * 8];

    float xnr[2][4];
#pragma unroll
    for (int m = 0; m < 2; ++m)
#pragma unroll
        for (int i = 0; i < 4; ++i)
            xnr[m][i] = xpn[row0 + m * 16 + lg * 4 + i];

    float oacc[2][4][3] = {};  // [m][i][c]

    ProtoTile A, B;
    load_tile(A, lpb, lpn, pps, pbase, lr, lg);

#pragma unroll
    for (int tt = 0; tt < 16; tt += 2) {
        if (tt + 1 < 16) load_tile(B, lpb, lpn, pps, pbase + (tt + 1) * 16, lr, lg);
        compute_tile(A, af, xnr, oacc, sim, row0, pbase + tt * 16, lr, lg);
        if (tt + 2 < 16) load_tile(A, lpb, lpn, pps, pbase + (tt + 2) * 16, lr, lg);
        compute_tile(B, af, xnr, oacc, sim, row0, pbase + (tt + 1) * 16, lr, lg);
    }

#pragma unroll
    for (int m = 0; m < 2; ++m)
#pragma unroll
        for (int i = 0; i < 4; ++i)
#pragma unroll
            for (int c = 0; c < 3; ++c) {
                float v = oacc[m][i][c];
                v += __shfl_xor(v, 1, 64);
                v += __shfl_xor(v, 2, 64);
                v += __shfl_xor(v, 4, 64);
                v += __shfl_xor(v, 8, 64);
                if (lr == 0)
                    atomicAdd(&out1[(size_t)(row0 + m * 16 + lg * 4 + i) * Cn + c], v);
            }
}

__global__ void finalize_kernel(const float* __restrict__ o1, float* __restrict__ out2) {
    int i = blockIdx.x * 256 + threadIdx.x;
    if (i < Bn * Cn) {
        float v = o1[i];
        int c = i - (i / Cn) * Cn;
        out2[i] = (c == 0) ? tanhf(v) : fmaxf(v, 0.f);
    }
}

extern "C" void kernel_launch(void* const* d_in, const int* in_sizes, int n_in,
                              void* d_out, int out_size, void* d_ws, size_t ws_size,
                              hipStream_t stream) {
    const float* x    = (const float*)d_in[0];
    const float* prot = (const float*)d_in[2];
    const float* pres = (const float*)d_in[3];
    const float* W1   = (const float*)d_in[4];
    const float* b1   = (const float*)d_in[5];
    const float* W2   = (const float*)d_in[6];
    const float* b2   = (const float*)d_in[7];

    float* out  = (float*)d_out;
    float* out2 = out;                           // [B,3]
    float* xp   = out + (size_t)Bn * Cn;         // [B,50]
    float* sim  = xp + (size_t)Bn * Dn;          // [B,1024]
    float* pp   = sim + (size_t)Bn * Pn;         // [3,1024,10]

    float* ws     = (float*)d_ws;
    float* out1ws = ws;                          // [B,3]
    float* pps    = out1ws + (size_t)Bn * Cn;    // [3,P]  (adjacent -> one memset)
    float* xpn    = pps + Cn * Pn;               // [B]
    float* lpn    = xpn + Bn;                    // [P]
    float* lpf    = lpn + Pn;                    // [P,50] fp32 proto projection (unused downstream)
    unsigned short* xpb = (unsigned short*)(lpf + Pn * Dn);  // [B,64] bf16
    unsigned short* lpb = xpb + (size_t)Bn * 64;             // [P,64] bf16

    hipMemsetAsync(out1ws, 0, ((size_t)Bn * Cn + Cn * Pn) * sizeof(float), stream);
    hipLaunchKernelGGL(pp_softmax_kernel, dim3(Cn * Sn), dim3(64), 0, stream, pres, pp, pps);
    hipLaunchKernelGGL(project_kernel, dim3(Bn / 64), dim3(256), 0, stream,
                       x, W1, b1, W2, b2, xp, xpn, xpb);
    hipLaunchKernelGGL(project_kernel, dim3(Pn / 64), dim3(256), 0, stream,
                       prot, W1, b1, W2, b2, lpf, lpn, lpb);
    hipLaunchKernelGGL(sim_mfma_kernel, dim3(Bn / 32), dim3(256), 0, stream,
                       xpb, lpb, xpn, lpn, pps, sim, out1ws);
    hipLaunchKernelGGL(finalize_kernel, dim3((Bn * Cn + 255) / 256), dim3(256), 0, stream,
                       out1ws, out2);
}

// Round 9
// 287.720 us; speedup vs baseline: 2.3756x; 1.0059x over previous
//
#include <hip/hip_runtime.h>
#include <cmath>

#define Bn 32768
#define Ln 256
#define Pn 1024
#define Dn 50
#define Cn 3
#define Sn 10

typedef short bf16x8 __attribute__((ext_vector_type(8)));
typedef float f32x4 __attribute__((ext_vector_type(4)));

__device__ inline unsigned short f2bf(float f) {
    unsigned int u = __float_as_uint(f);
    unsigned int r = (u + 0x7FFFu + ((u >> 16) & 1u)) >> 16;
    return (unsigned short)r;
}

// ---------------- pp softmax over axis=1 (p), per (c,n); accumulates lmeta[p].{y,z,w} = pps[c][p] ----------------
__global__ void pp_softmax_kernel(const float* __restrict__ pres, float* __restrict__ pp,
                                  float* __restrict__ lmeta) {
    int c = blockIdx.x / Sn;
    int n = blockIdx.x % Sn;
    int lane = threadIdx.x; // 64 threads
    const float* src = pres + (size_t)c * Pn * Sn + n;
    float* dst = pp + (size_t)c * Pn * Sn + n;
    float v[16];
    float mx = -1e30f;
#pragma unroll
    for (int i = 0; i < 16; ++i) { v[i] = src[(size_t)(lane + i * 64) * Sn]; mx = fmaxf(mx, v[i]); }
#pragma unroll
    for (int m = 1; m < 64; m <<= 1) mx = fmaxf(mx, __shfl_xor(mx, m, 64));
    float sum = 0.f;
#pragma unroll
    for (int i = 0; i < 16; ++i) { v[i] = __expf(v[i] - mx); sum += v[i]; }
#pragma unroll
    for (int m = 1; m < 64; m <<= 1) sum += __shfl_xor(sum, m, 64);
    float inv = 1.0f / sum;
#pragma unroll
    for (int i = 0; i < 16; ++i) {
        float r = v[i] * inv;
        int p = lane + i * 64;
        dst[(size_t)p * Sn] = r;
        atomicAdd(&lmeta[p * 4 + 1 + c], r);
    }
}

// ---------------- projection: Linear(256->50) -> InstanceNorm -> ReLU -> Linear(50->50) ----------------
__global__ __launch_bounds__(256) void project_kernel(
    const float* __restrict__ zin,
    const float* __restrict__ W1, const float* __restrict__ b1,
    const float* __restrict__ W2, const float* __restrict__ b2,
    float* __restrict__ outp, float* __restrict__ outn, int nstride,
    unsigned short* __restrict__ outb)
{
    __shared__ float xs[64][68];
    __shared__ float w1t[64][68];
    __shared__ float w2t[52][68];

    int t = threadIdx.x;
    int tx = t & 15, ty = t >> 4;
    int row0 = blockIdx.x * 64;

    for (int idx = t; idx < 52 * 64; idx += 256) {
        int j = idx & 63, k = idx >> 6;
        w2t[k][j] = (j < Dn && k < Dn) ? W2[j * Dn + k] : 0.f;
    }

    float acc[4][4] = {};
    for (int kc = 0; kc < Ln; kc += 64) {
        __syncthreads();
        for (int idx = t; idx < 64 * 64; idx += 256) {
            int kk = idx & 63, r = idx >> 6;
            xs[r][kk] = zin[(size_t)(row0 + r) * Ln + kc + kk];
        }
        for (int idx = t; idx < 64 * 64; idx += 256) {
            int j = idx & 63, kk = idx >> 6;
            w1t[kk][j] = (j < Dn) ? W1[j * Ln + kc + kk] : 0.f;
        }
        __syncthreads();
#pragma unroll 4
        for (int k4 = 0; k4 < 16; ++k4) {
            float4 xv[4], wv[4];
#pragma unroll
            for (int i = 0; i < 4; ++i) xv[i] = *(const float4*)&xs[ty * 4 + i][k4 * 4];
#pragma unroll
            for (int kk = 0; kk < 4; ++kk) wv[kk] = *(const float4*)&w1t[k4 * 4 + kk][tx * 4];
#pragma unroll
            for (int i = 0; i < 4; ++i)
#pragma unroll
                for (int kk = 0; kk < 4; ++kk)
#pragma unroll
                    for (int j = 0; j < 4; ++j)
                        acc[i][j] += (&xv[i].x)[kk] * (&wv[kk].x)[j];
        }
    }

    float rb1[4], rb2[4];
    bool valid[4];
#pragma unroll
    for (int j = 0; j < 4; ++j) {
        int c = tx * 4 + j;
        valid[j] = c < Dn;
        rb1[j] = valid[j] ? b1[c] : 0.f;
        rb2[j] = valid[j] ? b2[c] : 0.f;
    }

    __syncthreads();

#pragma unroll
    for (int i = 0; i < 4; ++i) {
        float h[4];
        float s = 0.f;
#pragma unroll
        for (int j = 0; j < 4; ++j) { h[j] = acc[i][j] + rb1[j]; s += h[j]; }
#pragma unroll
        for (int m = 1; m < 16; m <<= 1) s += __shfl_xor(s, m, 64);
        float mean = s * (1.0f / Dn);
        float s2 = 0.f;
#pragma unroll
        for (int j = 0; j < 4; ++j) { float dv = valid[j] ? (h[j] - mean) : 0.f; s2 += dv * dv; }
#pragma unroll
        for (int m = 1; m < 16; m <<= 1) s2 += __shfl_xor(s2, m, 64);
        float rstd = rsqrtf(s2 * (1.0f / Dn) + 1e-5f);
        float4 rv;
#pragma unroll
        for (int j = 0; j < 4; ++j)
            (&rv.x)[j] = valid[j] ? fmaxf((h[j] - mean) * rstd, 0.f) : 0.f;
        *(float4*)&xs[ty * 4 + i][tx * 4] = rv;
    }
    __syncthreads();

    float acc2[4][4] = {};
#pragma unroll 4
    for (int k4 = 0; k4 < 13; ++k4) {
        float4 xv[4], wv[4];
#pragma unroll
        for (int i = 0; i < 4; ++i) xv[i] = *(const float4*)&xs[ty * 4 + i][k4 * 4];
#pragma unroll
        for (int kk = 0; kk < 4; ++kk) wv[kk] = *(const float4*)&w2t[k4 * 4 + kk][tx * 4];
#pragma unroll
        for (int i = 0; i < 4; ++i)
#pragma unroll
            for (int kk = 0; kk < 4; ++kk)
#pragma unroll
                for (int j = 0; j < 4; ++j)
                    acc2[i][j] += (&xv[i].x)[kk] * (&wv[kk].x)[j];
    }

#pragma unroll
    for (int i = 0; i < 4; ++i) {
        int row = row0 + ty * 4 + i;
        float o[4];
        float q = 0.f;
#pragma unroll
        for (int j = 0; j < 4; ++j) {
            o[j] = acc2[i][j] + rb2[j];
            if (valid[j]) q += o[j] * o[j];
            if (valid[j]) outp[(size_t)row * Dn + tx * 4 + j] = o[j];
        }
        ushort4 ob;
        ob.x = valid[0] ? f2bf(o[0]) : 0;
        ob.y = valid[1] ? f2bf(o[1]) : 0;
        ob.z = valid[2] ? f2bf(o[2]) : 0;
        ob.w = valid[3] ? f2bf(o[3]) : 0;
        *(ushort4*)&outb[(size_t)row * 64 + tx * 4] = ob;
#pragma unroll
        for (int m = 1; m < 16; m <<= 1) q += __shfl_xor(q, m, 64);
        if (tx == 0) outn[row * nstride] = q;
    }
}

// ---------------- sim via bf16 MFMA, 32 rows/block, static dbuf, packed meta, LDS out2 reduce ----------------
struct ProtoTile {
    bf16x8 b0, b1;
    float4 meta;  // {lpn, pps0, pps1, pps2}
};

__device__ __forceinline__ void load_tile(ProtoTile& T,
    const unsigned short* __restrict__ lpb, const float4* __restrict__ lmeta,
    int pc, int lr, int lg)
{
    T.b0 = *(const bf16x8*)&lpb[(size_t)(pc + lr) * 64 + lg * 8];
    T.b1 = *(const bf16x8*)&lpb[(size_t)(pc + lr) * 64 + 32 + lg * 8];
    T.meta = lmeta[pc + lr];
}

__device__ __forceinline__ void compute_tile(const ProtoTile& T,
    const bf16x8 af[2][2], const float xnr[2][4], float oacc[2][4][3],
    float* __restrict__ sim, int row0, int pc, int lr, int lg)
{
    f32x4 acc[2];
#pragma unroll
    for (int m = 0; m < 2; ++m) { f32x4 z = {0.f, 0.f, 0.f, 0.f}; acc[m] = z; }
#pragma unroll
    for (int m = 0; m < 2; ++m) {
        acc[m] = __builtin_amdgcn_mfma_f32_16x16x32_bf16(af[m][0], T.b0, acc[m], 0, 0, 0);
        acc[m] = __builtin_amdgcn_mfma_f32_16x16x32_bf16(af[m][1], T.b1, acc[m], 0, 0, 0);
    }
#pragma unroll
    for (int m = 0; m < 2; ++m)
#pragma unroll
        for (int i = 0; i < 4; ++i) {
            float l2 = xnr[m][i] + T.meta.x - 2.f * acc[m][i];
            l2 = fmaxf(l2, 0.f);
            float s = __logf(__fdividef(l2 + 1.f, l2 + 1e-5f));
            sim[(size_t)(row0 + m * 16 + lg * 4 + i) * Pn + pc + lr] = s;
            oacc[m][i][0] += s * T.meta.y;
            oacc[m][i][1] += s * T.meta.z;
            oacc[m][i][2] += s * T.meta.w;
        }
}

__global__ __launch_bounds__(256) void sim_mfma_kernel(
    const unsigned short* __restrict__ xpb, const unsigned short* __restrict__ lpb,
    const float* __restrict__ xpn, const float4* __restrict__ lmeta,
    float* __restrict__ sim, float* __restrict__ out2)
{
    __shared__ float redc[96];  // 32 rows x 3 classes

    int t = threadIdx.x;
    int w = t >> 6, l = t & 63;
    int lr = l & 15, lg = l >> 4;
    int row0 = blockIdx.x * 32;
    int pbase = w * 256;

    if (t < 96) redc[t] = 0.f;

    bf16x8 af[2][2];
#pragma unroll
    for (int m = 0; m < 2; ++m)
#pragma unroll
        for (int ks = 0; ks < 2; ++ks)
            af[m][ks] = *(const bf16x8*)&xpb[(size_t)(row0 + m * 16 + lr) * 64 + ks * 32 + lg * 8];

    float xnr[2][4];
#pragma unroll
    for (int m = 0; m < 2; ++m) {
        float4 xv = *(const float4*)&xpn[row0 + m * 16 + lg * 4];
        xnr[m][0] = xv.x; xnr[m][1] = xv.y; xnr[m][2] = xv.z; xnr[m][3] = xv.w;
    }

    float oacc[2][4][3] = {};  // [m][i][c]

    ProtoTile A, B;
    load_tile(A, lpb, lmeta, pbase, lr, lg);

    __syncthreads();  // redc zero-init visible before atomics

#pragma unroll
    for (int tt = 0; tt < 16; tt += 2) {
        if (tt + 1 < 16) load_tile(B, lpb, lmeta, pbase + (tt + 1) * 16, lr, lg);
        compute_tile(A, af, xnr, oacc, sim, row0, pbase + tt * 16, lr, lg);
        if (tt + 2 < 16) load_tile(A, lpb, lmeta, pbase + (tt + 2) * 16, lr, lg);
        compute_tile(B, af, xnr, oacc, sim, row0, pbase + (tt + 1) * 16, lr, lg);
    }

#pragma unroll
    for (int m = 0; m < 2; ++m)
#pragma unroll
        for (int i = 0; i < 4; ++i)
#pragma unroll
            for (int c = 0; c < 3; ++c) {
                float v = oacc[m][i][c];
                v += __shfl_xor(v, 1, 64);
                v += __shfl_xor(v, 2, 64);
                v += __shfl_xor(v, 4, 64);
                v += __shfl_xor(v, 8, 64);
                if (lr == 0)
                    atomicAdd(&redc[(m * 16 + lg * 4 + i) * 3 + c], v);
            }

    __syncthreads();
    if (t < 96) {
        int c = t - (t / 3) * 3;
        float v = redc[t];
        out2[(size_t)row0 * 3 + t] = (c == 0) ? tanhf(v) : fmaxf(v, 0.f);
    }
}

extern "C" void kernel_launch(void* const* d_in, const int* in_sizes, int n_in,
                              void* d_out, int out_size, void* d_ws, size_t ws_size,
                              hipStream_t stream) {
    const float* x    = (const float*)d_in[0];
    const float* prot = (const float*)d_in[2];
    const float* pres = (const float*)d_in[3];
    const float* W1   = (const float*)d_in[4];
    const float* b1   = (const float*)d_in[5];
    const float* W2   = (const float*)d_in[6];
    const float* b2   = (const float*)d_in[7];

    float* out  = (float*)d_out;
    float* out2 = out;                           // [B,3]
    float* xp   = out + (size_t)Bn * Cn;         // [B,50]
    float* sim  = xp + (size_t)Bn * Dn;          // [B,1024]
    float* pp   = sim + (size_t)Bn * Pn;         // [3,1024,10]

    float* ws     = (float*)d_ws;
    float* lmeta  = ws;                          // [P,4] = {lpn, pps0, pps1, pps2}
    float* xpn    = lmeta + (size_t)Pn * 4;      // [B]
    float* lpf    = xpn + Bn;                    // [P,50] fp32 proto projection (unused downstream)
    unsigned short* xpb = (unsigned short*)(lpf + Pn * Dn);  // [B,64] bf16
    unsigned short* lpb = xpb + (size_t)Bn * 64;             // [P,64] bf16

    hipMemsetAsync(lmeta, 0, (size_t)Pn * 4 * sizeof(float), stream);
    hipLaunchKernelGGL(pp_softmax_kernel, dim3(Cn * Sn), dim3(64), 0, stream, pres, pp, lmeta);
    hipLaunchKernelGGL(project_kernel, dim3(Bn / 64), dim3(256), 0, stream,
                       x, W1, b1, W2, b2, xp, xpn, 1, xpb);
    hipLaunchKernelGGL(project_kernel, dim3(Pn / 64), dim3(256), 0, stream,
                       prot, W1, b1, W2, b2, lpf, lmeta, 4, lpb);
    hipLaunchKernelGGL(sim_mfma_kernel, dim3(Bn / 32), dim3(256), 0, stream,
                       xpb, lpb, xpn, (const float4*)lmeta, sim, out2);
}